// Round 1
// baseline (697.513 us; speedup 1.0000x reference)
//
#include <hip/hip_runtime.h>
#include <hip/hip_bf16.h>

// Problem constants (B=1)
#define SEQ   2048
#define DM    4096     // model dim
#define NH    32       // q heads
#define NKVH  8        // kv heads
#define HD    128      // head dim
#define NQKV  6144     // 4096 q + 1024 k + 1024 v
#define KOFF  4096     // col offset of K in fused qkv
#define VOFF  5120     // col offset of V
#define SCALE 0.08838834764831845f

typedef __attribute__((ext_vector_type(4))) float f32x4;
typedef __attribute__((ext_vector_type(8))) short short8;

__device__ __forceinline__ unsigned short f2bf(float f) {
  union { float f; unsigned int u; } v; v.f = f;
  unsigned int r = v.u + 0x7FFF + ((v.u >> 16) & 1);
  return (unsigned short)(r >> 16);
}
__device__ __forceinline__ float bf2f(unsigned short b) {
  union { unsigned int u; float f; } v; v.u = ((unsigned int)b) << 16;
  return v.f;
}

// ---------------- elementwise fp32 -> bf16 cast (hs) ----------------
__global__ __launch_bounds__(256) void cast_f32_bf16(const float* __restrict__ in,
                                                     unsigned short* __restrict__ out) {
  size_t i = ((size_t)blockIdx.x * 256 + threadIdx.x) * 4;
  float4 v = *(const float4*)(in + i);
  ushort4 o;
  o.x = f2bf(v.x); o.y = f2bf(v.y); o.z = f2bf(v.z); o.w = f2bf(v.w);
  *(ushort4*)(out + i) = o;
}

// ---------------- transpose + cast: W (KxN fp32, row-major) -> Wt[(row_off+n)*K + k] bf16 ----
__global__ __launch_bounds__(256) void transpose_cast(const float* __restrict__ W,
                                                      unsigned short* __restrict__ Wt,
                                                      int K, int N, int row_off) {
  __shared__ float tile[32][33];
  int n0 = blockIdx.x * 32, k0 = blockIdx.y * 32;
  int x = threadIdx.x & 31, y4 = (threadIdx.x >> 5) * 4;
#pragma unroll
  for (int i = 0; i < 4; ++i)
    tile[y4 + i][x] = W[(size_t)(k0 + y4 + i) * N + n0 + x];
  __syncthreads();
#pragma unroll
  for (int i = 0; i < 4; ++i)
    Wt[(size_t)(row_off + n0 + y4 + i) * K + k0 + x] = f2bf(tile[x][y4 + i]);
}

// ---------------- GEMM: C[M,N] = A[M,K] @ Bt[N,K]^T, bf16 in, fp32 acc ----------------
// 128x128 block tile, BK=32, 4 waves each 64x64 (4x4 of 16x16 mfma tiles).
// LDS rows padded 32->40 elements: frag ds_read_b128 lands 2-way bank aliasing (free).
__global__ __launch_bounds__(256) void gemm_bt(const unsigned short* __restrict__ A,
                                               const unsigned short* __restrict__ Bt,
                                               void* __restrict__ C,
                                               int M, int N, int K, int c_fp32) {
  __shared__ unsigned short As[128 * 40];
  __shared__ unsigned short Bs[128 * 40];
  const int tid  = threadIdx.x;
  const int m0   = blockIdx.y * 128;
  const int n0   = blockIdx.x * 128;
  const int w    = tid >> 6;
  const int lane = tid & 63;
  const int l16  = lane & 15;
  const int quad = lane >> 4;
  const int wr   = (w >> 1) * 64;
  const int wc   = (w & 1) * 64;

  f32x4 acc[4][4];
#pragma unroll
  for (int i = 0; i < 4; ++i)
#pragma unroll
    for (int j = 0; j < 4; ++j) acc[i][j] = (f32x4){0.f, 0.f, 0.f, 0.f};

  const int srow = tid >> 2;          // 0..63
  const int scol = (tid & 3) * 8;     // 0,8,16,24
  const unsigned short* ag  = A  + (size_t)(m0 + srow) * K + scol;
  const unsigned short* ag2 = A  + (size_t)(m0 + 64 + srow) * K + scol;
  const unsigned short* bg  = Bt + (size_t)(n0 + srow) * K + scol;
  const unsigned short* bg2 = Bt + (size_t)(n0 + 64 + srow) * K + scol;

  for (int k0 = 0; k0 < K; k0 += 32) {
    short8 va  = *(const short8*)(ag  + k0);
    short8 va2 = *(const short8*)(ag2 + k0);
    short8 vb  = *(const short8*)(bg  + k0);
    short8 vb2 = *(const short8*)(bg2 + k0);
    __syncthreads();
    *(short8*)&As[srow * 40 + scol]        = va;
    *(short8*)&As[(64 + srow) * 40 + scol] = va2;
    *(short8*)&Bs[srow * 40 + scol]        = vb;
    *(short8*)&Bs[(64 + srow) * 40 + scol] = vb2;
    __syncthreads();
    short8 af[4], bfr[4];
#pragma unroll
    for (int mt = 0; mt < 4; ++mt)
      af[mt] = *(const short8*)&As[(wr + mt * 16 + l16) * 40 + quad * 8];
#pragma unroll
    for (int nt = 0; nt < 4; ++nt)
      bfr[nt] = *(const short8*)&Bs[(wc + nt * 16 + l16) * 40 + quad * 8];
#pragma unroll
    for (int mt = 0; mt < 4; ++mt)
#pragma unroll
      for (int nt = 0; nt < 4; ++nt)
        acc[mt][nt] = __builtin_amdgcn_mfma_f32_16x16x32_bf16(af[mt], bfr[nt], acc[mt][nt], 0, 0, 0);
  }

  if (c_fp32) {
    float* Cf = (float*)C;
#pragma unroll
    for (int mt = 0; mt < 4; ++mt)
#pragma unroll
      for (int nt = 0; nt < 4; ++nt) {
        int col = n0 + wc + nt * 16 + l16;
#pragma unroll
        for (int r = 0; r < 4; ++r)
          Cf[(size_t)(m0 + wr + mt * 16 + quad * 4 + r) * N + col] = acc[mt][nt][r];
      }
  } else {
    unsigned short* Cb = (unsigned short*)C;
#pragma unroll
    for (int mt = 0; mt < 4; ++mt)
#pragma unroll
      for (int nt = 0; nt < 4; ++nt) {
        int col = n0 + wc + nt * 16 + l16;
#pragma unroll
        for (int r = 0; r < 4; ++r)
          Cb[(size_t)(m0 + wr + mt * 16 + quad * 4 + r) * N + col] = f2bf(acc[mt][nt][r]);
      }
  }
}

// ---------------- RoPE in-place on fused qkv (bf16), heads 0..39 = 32 q + 8 k ----------------
__global__ __launch_bounds__(256) void rope_kernel(unsigned short* __restrict__ QKV,
                                                   const float* __restrict__ cosb,
                                                   const float* __restrict__ sinb) {
  int idx = blockIdx.x * 256 + threadIdx.x;   // s * 40 * 64
  int i = idx & 63;
  int h = (idx >> 6) % 40;
  int s = idx / 2560;
  size_t base = (size_t)s * NQKV + (size_t)h * 128;   // h=32..39 lands exactly on K cols
  float q1 = bf2f(QKV[base + i]);
  float q2 = bf2f(QKV[base + i + 64]);
  float c1 = cosb[s * 128 + i],     s1 = sinb[s * 128 + i];
  float c2 = cosb[s * 128 + i + 64], s2 = sinb[s * 128 + i + 64];
  QKV[base + i]      = f2bf(q1 * c1 - q2 * s1);
  QKV[base + i + 64] = f2bf(q2 * c2 + q1 * s2);
}

// ---------------- flash attention: block = (head, 64-row q tile), 4 waves x 16 rows ----------
__global__ __launch_bounds__(256) void flash_attn(const unsigned short* __restrict__ QKV,
                                                  unsigned short* __restrict__ AO) {
  __shared__ unsigned short Ks[32 * 136];   // [key][hd], padded 128->136
  __shared__ unsigned short Vt[128 * 40];   // [hd][key], padded 32->40
  __shared__ unsigned short Ps[4][16 * 40]; // per-wave P tile, padded

  const int h   = blockIdx.x;          // 0..31
  const int qt  = blockIdx.y;          // 0..31
  const int kvh = h >> 2;              // GROUPS = 4
  const int tid  = threadIdx.x;
  const int w    = tid >> 6;
  const int lane = tid & 63;
  const int l16  = lane & 15;
  const int quad = lane >> 4;

  // Q A-frags: rows qt*64 + w*16 + l16, k = ks*32 + quad*8 + j
  const int qrow_a = qt * 64 + w * 16 + l16;
  short8 a_q[4];
  const unsigned short* qptr = QKV + (size_t)qrow_a * NQKV + h * HD + quad * 8;
#pragma unroll
  for (int ks = 0; ks < 4; ++ks) a_q[ks] = *(const short8*)(qptr + ks * 32);

  f32x4 o_acc[8];
#pragma unroll
  for (int i = 0; i < 8; ++i) o_acc[i] = (f32x4){0.f, 0.f, 0.f, 0.f};
  float m_i[4], l_i[4];
#pragma unroll
  for (int r = 0; r < 4; ++r) { m_i[r] = -3.0e38f; l_i[r] = 0.f; }

  const int qrow_c = qt * 64 + w * 16 + quad * 4;   // + r
  const int skey = tid >> 3;          // staging key 0..31
  const int scol = (tid & 7) * 16;    // staging hd col
  const int nchunks = qt * 2 + 2;

  for (int c = 0; c < nchunks; ++c) {
    const int kc = c * 32;
    // stage K chunk [key][hd] and V chunk transposed [hd][key]
    const unsigned short* ksrc = QKV + (size_t)(kc + skey) * NQKV + KOFF + kvh * HD + scol;
    const unsigned short* vsrc = QKV + (size_t)(kc + skey) * NQKV + VOFF + kvh * HD + scol;
    short8 k0v = *(const short8*)(ksrc);
    short8 k1v = *(const short8*)(ksrc + 8);
    short8 v0v = *(const short8*)(vsrc);
    short8 v1v = *(const short8*)(vsrc + 8);
    __syncthreads();   // previous chunk's reads complete
    *(short8*)&Ks[skey * 136 + scol]     = k0v;
    *(short8*)&Ks[skey * 136 + scol + 8] = k1v;
#pragma unroll
    for (int i = 0; i < 8; ++i) {
      Vt[(scol + i) * 40 + skey]     = (unsigned short)((unsigned short*)&v0v)[i];
      Vt[(scol + 8 + i) * 40 + skey] = (unsigned short)((unsigned short*)&v1v)[i];
    }
    __syncthreads();

    // S = Q @ K^T  (2 n-tiles of 16 keys, 4 k-steps of 32 hd)
    f32x4 s_acc[2];
    s_acc[0] = (f32x4){0.f, 0.f, 0.f, 0.f};
    s_acc[1] = (f32x4){0.f, 0.f, 0.f, 0.f};
#pragma unroll
    for (int ks = 0; ks < 4; ++ks) {
      short8 bk0 = *(const short8*)&Ks[l16 * 136 + ks * 32 + quad * 8];
      short8 bk1 = *(const short8*)&Ks[(16 + l16) * 136 + ks * 32 + quad * 8];
      s_acc[0] = __builtin_amdgcn_mfma_f32_16x16x32_bf16(a_q[ks], bk0, s_acc[0], 0, 0, 0);
      s_acc[1] = __builtin_amdgcn_mfma_f32_16x16x32_bf16(a_q[ks], bk1, s_acc[1], 0, 0, 0);
    }

    // scale + causal mask (-inf so fully-masked chunks give p = 0)
    float sc[2][4];
#pragma unroll
    for (int nt = 0; nt < 2; ++nt) {
      int key = kc + nt * 16 + l16;
#pragma unroll
      for (int r = 0; r < 4; ++r) {
        float v = s_acc[nt][r] * SCALE;
        sc[nt][r] = (key <= qrow_c + r) ? v : -__builtin_inff();
      }
    }
    // row max across the 16 lanes of this quad
    float mx[4];
#pragma unroll
    for (int r = 0; r < 4; ++r) mx[r] = fmaxf(sc[0][r], sc[1][r]);
#pragma unroll
    for (int off = 1; off < 16; off <<= 1)
#pragma unroll
      for (int r = 0; r < 4; ++r) mx[r] = fmaxf(mx[r], __shfl_xor(mx[r], off, 64));

    float alpha[4], mnew[4];
#pragma unroll
    for (int r = 0; r < 4; ++r) {
      mnew[r] = fmaxf(m_i[r], mx[r]);
      alpha[r] = __expf(m_i[r] - mnew[r]);   // both -3e38 first time -> exp(0)=1, l=0 anyway
      m_i[r] = mnew[r];
    }

    float rs[4] = {0.f, 0.f, 0.f, 0.f};
    unsigned short pb[2][4];
#pragma unroll
    for (int nt = 0; nt < 2; ++nt)
#pragma unroll
      for (int r = 0; r < 4; ++r) {
        float p = __expf(sc[nt][r] - mnew[r]);   // exp(-inf)=0 for masked
        rs[r] += p;
        pb[nt][r] = f2bf(p);
      }
#pragma unroll
    for (int off = 1; off < 16; off <<= 1)
#pragma unroll
      for (int r = 0; r < 4; ++r) rs[r] += __shfl_xor(rs[r], off, 64);
#pragma unroll
    for (int r = 0; r < 4; ++r) l_i[r] = l_i[r] * alpha[r] + rs[r];

#pragma unroll
    for (int i = 0; i < 8; ++i) {
      o_acc[i][0] *= alpha[0]; o_acc[i][1] *= alpha[1];
      o_acc[i][2] *= alpha[2]; o_acc[i][3] *= alpha[3];
    }

    // P: C-layout -> A-layout via wave-private LDS round-trip
    unsigned short* ps = &Ps[w][0];
#pragma unroll
    for (int nt = 0; nt < 2; ++nt)
#pragma unroll
      for (int r = 0; r < 4; ++r)
        ps[(quad * 4 + r) * 40 + nt * 16 + l16] = pb[nt][r];
    short8 a_p = *(const short8*)&ps[l16 * 40 + quad * 8];

    // O += P @ V  (8 hd-tiles, K=32 keys)
#pragma unroll
    for (int nt = 0; nt < 8; ++nt) {
      short8 b_v = *(const short8*)&Vt[(nt * 16 + l16) * 40 + quad * 8];
      o_acc[nt] = __builtin_amdgcn_mfma_f32_16x16x32_bf16(a_p, b_v, o_acc[nt], 0, 0, 0);
    }
  }

  float inv_l[4];
#pragma unroll
  for (int r = 0; r < 4; ++r) inv_l[r] = 1.0f / l_i[r];
#pragma unroll
  for (int nt = 0; nt < 8; ++nt) {
    int col = h * HD + nt * 16 + l16;
#pragma unroll
    for (int r = 0; r < 4; ++r)
      AO[(size_t)(qrow_c + r) * DM + col] = f2bf(o_acc[nt][r] * inv_l[r]);
  }
}

extern "C" void kernel_launch(void* const* d_in, const int* in_sizes, int n_in,
                              void* d_out, int out_size, void* d_ws, size_t ws_size,
                              hipStream_t stream) {
  const float* hs   = (const float*)d_in[0];
  const float* cosb = (const float*)d_in[1];
  const float* sinb = (const float*)d_in[2];
  // d_in[3] attention_mask: all ones in this problem -> causal-only
  const float* wq = (const float*)d_in[4];
  const float* wk = (const float*)d_in[5];
  const float* wv = (const float*)d_in[6];
  const float* wo = (const float*)d_in[7];
  float* out = (float*)d_out;

  char* ws = (char*)d_ws;
  unsigned short* hsb   = (unsigned short*)(ws);                      // 16 MB: hs bf16
  unsigned short* wqkvT = (unsigned short*)(ws + (16u << 20));        // 48 MB: [wq|wk|wv]^T bf16 (6144 x 4096)
  unsigned short* woT   = (unsigned short*)(ws + (64u << 20));        // 32 MB: wo^T bf16 (4096 x 4096)
  unsigned short* qkv   = (unsigned short*)(ws + (96u << 20));        // 24 MB: fused QKV bf16 (2048 x 6144)
  unsigned short* ao    = (unsigned short*)(ws + (120u << 20));       // 16 MB: attn out bf16 (2048 x 4096)

  cast_f32_bf16<<<8192, 256, 0, stream>>>(hs, hsb);
  transpose_cast<<<dim3(128, 128), 256, 0, stream>>>(wq, wqkvT, 4096, 4096, 0);
  transpose_cast<<<dim3(32, 128), 256, 0, stream>>>(wk, wqkvT, 4096, 1024, 4096);
  transpose_cast<<<dim3(32, 128), 256, 0, stream>>>(wv, wqkvT, 4096, 1024, 5120);
  transpose_cast<<<dim3(128, 128), 256, 0, stream>>>(wo, woT, 4096, 4096, 0);

  gemm_bt<<<dim3(NQKV / 128, SEQ / 128), 256, 0, stream>>>(hsb, wqkvT, qkv, SEQ, NQKV, DM, 0);
  rope_kernel<<<20480, 256, 0, stream>>>(qkv, cosb, sinb);
  flash_attn<<<dim3(NH, SEQ / 64), 256, 0, stream>>>(qkv, ao);
  gemm_bt<<<dim3(DM / 128, SEQ / 128), 256, 0, stream>>>(ao, woT, out, SEQ, DM, DM, 1);
}

// Round 2
// 573.153 us; speedup vs baseline: 1.2170x; 1.2170x over previous
//
#include <hip/hip_runtime.h>
#include <hip/hip_bf16.h>

// Problem constants (B=1)
#define SEQ   2048
#define DM    4096
#define NH    32
#define NKVH  8
#define HD    128
#define NQKV  6144
#define KOFF  4096
#define VOFF  5120
#define SCALE 0.08838834764831845f

typedef __attribute__((ext_vector_type(4))) float f32x4;
typedef __attribute__((ext_vector_type(8))) short short8;

__device__ __forceinline__ unsigned short f2bf(float f) {
  union { float f; unsigned int u; } v; v.f = f;
  unsigned int r = v.u + 0x7FFF + ((v.u >> 16) & 1);
  return (unsigned short)(r >> 16);
}
__device__ __forceinline__ float bf2f(unsigned short b) {
  union { unsigned int u; float f; } v; v.u = ((unsigned int)b) << 16;
  return v.f;
}

// async global->LDS, 16B per lane; LDS dest = wave-uniform base + lane*16
__device__ __forceinline__ void gld16(const unsigned short* g, unsigned short* l) {
  __builtin_amdgcn_global_load_lds(
      (const __attribute__((address_space(1))) unsigned int*)g,
      (__attribute__((address_space(3))) unsigned int*)l, 16, 0, 0);
}

// ---------------- elementwise fp32 -> bf16 cast (hs) ----------------
__global__ __launch_bounds__(256) void cast_f32_bf16(const float* __restrict__ in,
                                                     unsigned short* __restrict__ out) {
  size_t i = ((size_t)blockIdx.x * 256 + threadIdx.x) * 4;
  float4 v = *(const float4*)(in + i);
  ushort4 o;
  o.x = f2bf(v.x); o.y = f2bf(v.y); o.z = f2bf(v.z); o.w = f2bf(v.w);
  *(ushort4*)(out + i) = o;
}

// ---------------- transpose + cast: W (KxN fp32) -> Wt[(row_off+n)*K + k] bf16 ----
__global__ __launch_bounds__(256) void transpose_cast(const float* __restrict__ W,
                                                      unsigned short* __restrict__ Wt,
                                                      int K, int N, int row_off) {
  __shared__ float tile[32][33];
  int n0 = blockIdx.x * 32, k0 = blockIdx.y * 32;
  int x = threadIdx.x & 31, y4 = (threadIdx.x >> 5) * 4;
#pragma unroll
  for (int i = 0; i < 4; ++i)
    tile[y4 + i][x] = W[(size_t)(k0 + y4 + i) * N + n0 + x];
  __syncthreads();
#pragma unroll
  for (int i = 0; i < 4; ++i)
    Wt[(size_t)(row_off + n0 + y4 + i) * K + k0 + x] = f2bf(tile[x][y4 + i]);
}

// ---------------- bf16 transpose: qkv V cols -> Vt_g[kvh*128+hd][s] ----------------
__global__ __launch_bounds__(256) void v_transpose(const unsigned short* __restrict__ QKV,
                                                   unsigned short* __restrict__ Vt_g) {
  __shared__ unsigned short t[32][33];
  int s0 = blockIdx.x * 32, c0 = blockIdx.y * 32;
  int x = threadIdx.x & 31, y4 = (threadIdx.x >> 5) * 4;
#pragma unroll
  for (int i = 0; i < 4; ++i)
    t[y4 + i][x] = QKV[(size_t)(s0 + y4 + i) * NQKV + VOFF + c0 + x];
  __syncthreads();
#pragma unroll
  for (int i = 0; i < 4; ++i)
    Vt_g[(size_t)(c0 + y4 + i) * SEQ + s0 + x] = t[x][y4 + i];
}

// ---------------- GEMM: C[M,N] = A[M,K] @ Bt[N,K]^T, m97-style ----------------
// 128x128 tile, BK=32, global_load_lds width-16 staging into unpadded LDS with
// XOR k-block swizzle s(row)=(row&3)^((row>>2)&3) -> frag reads 2-way (free).
__global__ __launch_bounds__(256) void gemm_bt(const unsigned short* __restrict__ A,
                                               const unsigned short* __restrict__ Bt,
                                               void* __restrict__ C,
                                               int M, int N, int K, int c_fp32) {
  __shared__ unsigned short As[128 * 32];
  __shared__ unsigned short Bs[128 * 32];
  const int tid  = threadIdx.x;
  const int m0   = blockIdx.y * 128;
  const int n0   = blockIdx.x * 128;
  const int w    = tid >> 6;
  const int lane = tid & 63;
  const int l16  = lane & 15;
  const int quad = lane >> 4;
  const int wr   = (w >> 1) * 64;
  const int wc   = (w & 1) * 64;

  f32x4 acc[4][4];
#pragma unroll
  for (int i = 0; i < 4; ++i)
#pragma unroll
    for (int j = 0; j < 4; ++j) acc[i][j] = (f32x4){0.f, 0.f, 0.f, 0.f};

  // staging: lane covers row w*16 + (lane>>2) (and +64), physical k-block lane&3
  const int sr  = lane >> 2;
  const int pb  = lane & 3;
  const int sws = (sr & 3) ^ ((sr >> 2) & 3);           // swizzle for staged row
  const int kb  = ((pb ^ sws) << 3);                    // logical k offset (shorts)
  const unsigned short* ga0 = A  + (size_t)(m0 + w * 16 + sr) * K + kb;
  const unsigned short* ga1 = A  + (size_t)(m0 + 64 + w * 16 + sr) * K + kb;
  const unsigned short* gb0 = Bt + (size_t)(n0 + w * 16 + sr) * K + kb;
  const unsigned short* gb1 = Bt + (size_t)(n0 + 64 + w * 16 + sr) * K + kb;
  unsigned short* la0 = As + (w * 16) * 32;             // wave-uniform LDS bases
  unsigned short* la1 = As + (64 + w * 16) * 32;
  unsigned short* lb0 = Bs + (w * 16) * 32;
  unsigned short* lb1 = Bs + (64 + w * 16) * 32;

  const int swf  = (l16 & 3) ^ ((l16 >> 2) & 3);        // swizzle for frag row
  const int fcol = ((quad ^ swf) << 3);

  for (int k0 = 0; k0 < K; k0 += 32) {
    __syncthreads();                  // previous frag reads done
    gld16(ga0 + k0, la0);
    gld16(ga1 + k0, la1);
    gld16(gb0 + k0, lb0);
    gld16(gb1 + k0, lb1);
    __syncthreads();                  // drains vmcnt -> LDS visible
    short8 af[4], bfr[4];
#pragma unroll
    for (int mt = 0; mt < 4; ++mt)
      af[mt] = *(const short8*)&As[(wr + mt * 16 + l16) * 32 + fcol];
#pragma unroll
    for (int nt = 0; nt < 4; ++nt)
      bfr[nt] = *(const short8*)&Bs[(wc + nt * 16 + l16) * 32 + fcol];
#pragma unroll
    for (int mt = 0; mt < 4; ++mt)
#pragma unroll
      for (int nt = 0; nt < 4; ++nt)
        acc[mt][nt] = __builtin_amdgcn_mfma_f32_16x16x32_bf16(af[mt], bfr[nt], acc[mt][nt], 0, 0, 0);
  }

  if (c_fp32) {
    float* Cf = (float*)C;
#pragma unroll
    for (int mt = 0; mt < 4; ++mt)
#pragma unroll
      for (int nt = 0; nt < 4; ++nt) {
        int col = n0 + wc + nt * 16 + l16;
#pragma unroll
        for (int r = 0; r < 4; ++r)
          Cf[(size_t)(m0 + wr + mt * 16 + quad * 4 + r) * N + col] = acc[mt][nt][r];
      }
  } else {
    unsigned short* Cb = (unsigned short*)C;
#pragma unroll
    for (int mt = 0; mt < 4; ++mt)
#pragma unroll
      for (int nt = 0; nt < 4; ++nt) {
        int col = n0 + wc + nt * 16 + l16;
#pragma unroll
        for (int r = 0; r < 4; ++r)
          Cb[(size_t)(m0 + wr + mt * 16 + quad * 4 + r) * N + col] = f2bf(acc[mt][nt][r]);
      }
  }
}

// ---------------- RoPE in-place on fused qkv (bf16), heads 0..39 = 32 q + 8 k ----------------
__global__ __launch_bounds__(256) void rope_kernel(unsigned short* __restrict__ QKV,
                                                   const float* __restrict__ cosb,
                                                   const float* __restrict__ sinb) {
  int idx = blockIdx.x * 256 + threadIdx.x;
  int i = idx & 63;
  int h = (idx >> 6) % 40;
  int s = idx / 2560;
  size_t base = (size_t)s * NQKV + (size_t)h * 128;
  float q1 = bf2f(QKV[base + i]);
  float q2 = bf2f(QKV[base + i + 64]);
  float c1 = cosb[s * 128 + i],      s1 = sinb[s * 128 + i];
  float c2 = cosb[s * 128 + i + 64], s2 = sinb[s * 128 + i + 64];
  QKV[base + i]      = f2bf(q1 * c1 - q2 * s1);
  QKV[base + i + 64] = f2bf(q2 * c2 + q1 * s2);
}

// ---------------- flash attention v2: S^T formulation ----------------
// Block = (head, 128 q-rows), 4 waves x 32 rows (2 n-tiles). 64-key chunks.
// S^T = K@Q^T (A=K from LDS [key][hd], B=Q regs). P^T tile -> per-wave LDS
// [qrow][key] with b64 writes. O^T = V^T@P^T (A=V^T from LDS [hd][key]).
__global__ __launch_bounds__(256) void flash_attn(const unsigned short* __restrict__ QKV,
                                                  const unsigned short* __restrict__ Vt_g,
                                                  unsigned short* __restrict__ AO) {
  __shared__ unsigned short Ks[64 * 136];   // [key][hd] pad 128->136
  __shared__ unsigned short Vs[128 * 72];   // [hd][key] pad 64->72
  __shared__ unsigned short Ps[4][32 * 68]; // per-wave [qrow][key] pad 64->68

  const int h   = blockIdx.x;
  const int qt  = (int)gridDim.y - 1 - (int)blockIdx.y;   // big tiles dispatch first
  const int kvh = h >> 2;
  const int tid  = threadIdx.x;
  const int w    = tid >> 6;
  const int lane = tid & 63;
  const int l16  = lane & 15;
  const int quad = lane >> 4;
  const int q0   = qt * 128;
  const int qrow_w = q0 + w * 32;

  // Q B-frags (B layout == A layout: [n=l16][k=quad*8+j])
  short8 qf[2][4];
#pragma unroll
  for (int ntq = 0; ntq < 2; ++ntq) {
    const unsigned short* qp = QKV + (size_t)(qrow_w + ntq * 16 + l16) * NQKV + h * HD + quad * 8;
#pragma unroll
    for (int ks = 0; ks < 4; ++ks) qf[ntq][ks] = *(const short8*)(qp + ks * 32);
  }

  f32x4 o[8][2];
#pragma unroll
  for (int i = 0; i < 8; ++i) { o[i][0] = (f32x4){0,0,0,0}; o[i][1] = (f32x4){0,0,0,0}; }
  float m_i[2] = {-3.0e38f, -3.0e38f}, l_i[2] = {0.f, 0.f};

  // staging coords
  const int kr = tid >> 2, kcol0 = (tid & 3) * 32;     // K: 64 rows x 128 cols
  const int vr = tid >> 1, vcol0 = (tid & 1) * 32;     // V: 128 rows x 64 cols
  const unsigned short* kbase = QKV + KOFF + (size_t)kvh * HD + kcol0;
  const unsigned short* vbase = Vt_g + ((size_t)kvh * HD + vr) * SEQ + vcol0;

  const int nch = qt * 2 + 2;
  for (int c = 0; c < nch; ++c) {
    const int kc = c * 64;
    short8 kv[4], vv[4];
#pragma unroll
    for (int u = 0; u < 4; ++u) kv[u] = *(const short8*)(kbase + (size_t)(kc + kr) * NQKV + u * 8);
#pragma unroll
    for (int u = 0; u < 4; ++u) vv[u] = *(const short8*)(vbase + kc + u * 8);
    __syncthreads();
#pragma unroll
    for (int u = 0; u < 4; ++u) *(short8*)&Ks[kr * 136 + kcol0 + u * 8] = kv[u];
#pragma unroll
    for (int u = 0; u < 4; ++u) *(short8*)&Vs[vr * 72 + vcol0 + u * 8] = vv[u];
    __syncthreads();

    if (kc <= qrow_w + 31) {       // wave-uniform; skip fully-masked chunks
      // S^T = K @ Q^T : m-tiles = 4 key tiles, n-tiles = 2 qrow tiles
      f32x4 st[4][2];
#pragma unroll
      for (int mt = 0; mt < 4; ++mt) { st[mt][0] = (f32x4){0,0,0,0}; st[mt][1] = (f32x4){0,0,0,0}; }
#pragma unroll
      for (int ks = 0; ks < 4; ++ks)
#pragma unroll
        for (int mt = 0; mt < 4; ++mt) {
          short8 ak = *(const short8*)&Ks[(mt * 16 + l16) * 136 + ks * 32 + quad * 8];
          st[mt][0] = __builtin_amdgcn_mfma_f32_16x16x32_bf16(ak, qf[0][ks], st[mt][0], 0, 0, 0);
          st[mt][1] = __builtin_amdgcn_mfma_f32_16x16x32_bf16(ak, qf[1][ks], st[mt][1], 0, 0, 0);
        }

      // mask + scale; rows of S^T = keys, cols = qrows
      float sc[4][2][4];
#pragma unroll
      for (int mt = 0; mt < 4; ++mt)
#pragma unroll
        for (int ntq = 0; ntq < 2; ++ntq) {
          int qr = qrow_w + ntq * 16 + l16;
#pragma unroll
          for (int r = 0; r < 4; ++r) {
            int key = kc + mt * 16 + quad * 4 + r;
            float v = st[mt][ntq][r] * SCALE;
            sc[mt][ntq][r] = (key <= qr) ? v : -__builtin_inff();
          }
        }
      // per-qrow max: reduce over mt,r in-lane, then across the 4 quads
      float mx[2] = {-__builtin_inff(), -__builtin_inff()};
#pragma unroll
      for (int mt = 0; mt < 4; ++mt)
#pragma unroll
        for (int ntq = 0; ntq < 2; ++ntq)
#pragma unroll
          for (int r = 0; r < 4; ++r) mx[ntq] = fmaxf(mx[ntq], sc[mt][ntq][r]);
#pragma unroll
      for (int ntq = 0; ntq < 2; ++ntq) {
        mx[ntq] = fmaxf(mx[ntq], __shfl_xor(mx[ntq], 16, 64));
        mx[ntq] = fmaxf(mx[ntq], __shfl_xor(mx[ntq], 32, 64));
      }
      float al[2], mn[2];
#pragma unroll
      for (int ntq = 0; ntq < 2; ++ntq) {
        mn[ntq] = fmaxf(m_i[ntq], mx[ntq]);
        al[ntq] = __expf(m_i[ntq] - mn[ntq]);
        m_i[ntq] = mn[ntq];
      }

      // p = exp(s-m), row-sum, pack to bf16, write P^T tile (b64 stores)
      float rs[2] = {0.f, 0.f};
      unsigned short* psw = &Ps[w][0];
#pragma unroll
      for (int mt = 0; mt < 4; ++mt)
#pragma unroll
        for (int ntq = 0; ntq < 2; ++ntq) {
          float p0 = __expf(sc[mt][ntq][0] - mn[ntq]);
          float p1 = __expf(sc[mt][ntq][1] - mn[ntq]);
          float p2 = __expf(sc[mt][ntq][2] - mn[ntq]);
          float p3 = __expf(sc[mt][ntq][3] - mn[ntq]);
          rs[ntq] += (p0 + p1) + (p2 + p3);
          ushort4 pk; pk.x = f2bf(p0); pk.y = f2bf(p1); pk.z = f2bf(p2); pk.w = f2bf(p3);
          *(ushort4*)&psw[(ntq * 16 + l16) * 68 + mt * 16 + quad * 4] = pk;
        }
#pragma unroll
      for (int ntq = 0; ntq < 2; ++ntq) {
        rs[ntq] += __shfl_xor(rs[ntq], 16, 64);
        rs[ntq] += __shfl_xor(rs[ntq], 32, 64);
        l_i[ntq] = l_i[ntq] * al[ntq] + rs[ntq];
      }
#pragma unroll
      for (int i = 0; i < 8; ++i) {
        o[i][0][0] *= al[0]; o[i][0][1] *= al[0]; o[i][0][2] *= al[0]; o[i][0][3] *= al[0];
        o[i][1][0] *= al[1]; o[i][1][1] *= al[1]; o[i][1][2] *= al[1]; o[i][1][3] *= al[1];
      }

      // O^T += V^T @ P^T  (A = Vs rows, B = Ps rows; wave-private, no barrier)
#pragma unroll
      for (int ks = 0; ks < 2; ++ks) {
        short8 bp[2];
#pragma unroll
        for (int ntq = 0; ntq < 2; ++ntq) {
          union { ushort4 h[2]; short8 v; } u;
          const unsigned short* pp = &psw[(ntq * 16 + l16) * 68 + ks * 32 + quad * 8];
          u.h[0] = *(const ushort4*)(pp);
          u.h[1] = *(const ushort4*)(pp + 4);
          bp[ntq] = u.v;
        }
#pragma unroll
        for (int mt = 0; mt < 8; ++mt) {
          short8 av = *(const short8*)&Vs[(mt * 16 + l16) * 72 + ks * 32 + quad * 8];
          o[mt][0] = __builtin_amdgcn_mfma_f32_16x16x32_bf16(av, bp[0], o[mt][0], 0, 0, 0);
          o[mt][1] = __builtin_amdgcn_mfma_f32_16x16x32_bf16(av, bp[1], o[mt][1], 0, 0, 0);
        }
      }
    }
  }

  // epilogue: O^T C-layout -> AO[qrow][h*128+hd], 8B stores
  float inv[2] = {1.0f / l_i[0], 1.0f / l_i[1]};
#pragma unroll
  for (int mt = 0; mt < 8; ++mt)
#pragma unroll
    for (int ntq = 0; ntq < 2; ++ntq) {
      int qr = qrow_w + ntq * 16 + l16;
      int col = h * HD + mt * 16 + quad * 4;
      ushort4 ov;
      ov.x = f2bf(o[mt][ntq][0] * inv[ntq]);
      ov.y = f2bf(o[mt][ntq][1] * inv[ntq]);
      ov.z = f2bf(o[mt][ntq][2] * inv[ntq]);
      ov.w = f2bf(o[mt][ntq][3] * inv[ntq]);
      *(ushort4*)&AO[(size_t)qr * DM + col] = ov;
    }
}

extern "C" void kernel_launch(void* const* d_in, const int* in_sizes, int n_in,
                              void* d_out, int out_size, void* d_ws, size_t ws_size,
                              hipStream_t stream) {
  const float* hs   = (const float*)d_in[0];
  const float* cosb = (const float*)d_in[1];
  const float* sinb = (const float*)d_in[2];
  // d_in[3] attention_mask: all ones -> causal-only
  const float* wq = (const float*)d_in[4];
  const float* wk = (const float*)d_in[5];
  const float* wv = (const float*)d_in[6];
  const float* wo = (const float*)d_in[7];
  float* out = (float*)d_out;

  char* ws = (char*)d_ws;
  unsigned short* hsb   = (unsigned short*)(ws);                 // 16 MB (reused as Vt_g later)
  unsigned short* wqkvT = (unsigned short*)(ws + (16u << 20));   // 48 MB
  unsigned short* woT   = (unsigned short*)(ws + (64u << 20));   // 32 MB
  unsigned short* qkv   = (unsigned short*)(ws + (96u << 20));   // 24 MB
  unsigned short* ao    = (unsigned short*)(ws + (120u << 20));  // 16 MB
  unsigned short* Vt_g  = hsb;   // 4 MB; hsb is dead after the QKV GEMM

  cast_f32_bf16<<<8192, 256, 0, stream>>>(hs, hsb);
  transpose_cast<<<dim3(128, 128), 256, 0, stream>>>(wq, wqkvT, 4096, 4096, 0);
  transpose_cast<<<dim3(32, 128), 256, 0, stream>>>(wk, wqkvT, 4096, 1024, 4096);
  transpose_cast<<<dim3(32, 128), 256, 0, stream>>>(wv, wqkvT, 4096, 1024, 5120);
  transpose_cast<<<dim3(128, 128), 256, 0, stream>>>(wo, woT, 4096, 4096, 0);

  gemm_bt<<<dim3(NQKV / 128, SEQ / 128), 256, 0, stream>>>(hsb, wqkvT, qkv, SEQ, NQKV, DM, 0);
  rope_kernel<<<20480, 256, 0, stream>>>(qkv, cosb, sinb);
  v_transpose<<<dim3(64, 32), 256, 0, stream>>>(qkv, Vt_g);
  flash_attn<<<dim3(NH, SEQ / 128), 256, 0, stream>>>(qkv, Vt_g, ao);
  gemm_bt<<<dim3(DM / 128, SEQ / 128), 256, 0, stream>>>(ao, woT, out, SEQ, DM, DM, 1);
}